// Round 1
// baseline (27701.038 us; speedup 1.0000x reference)
//
#include <hip/hip_runtime.h>
#include <math.h>

#define HD  512
#define BB  512
#define TT  336
#define HOR 48

#define BM 32
#define BN 32
#define KT 32

__device__ __forceinline__ float sigmoidf_(float x) { return 1.0f / (1.0f + __expf(-x)); }

// MODE 0: encoder layer 0 (small x from src, K=8)
// MODE 1: encoder layer 1 (big x = a_t, K=512 for both gi and gh)
// MODE 2: decoder GRU cell (small x = [last_value, tf_t], K=9)
template<int MODE>
__global__ __launch_bounds__(256)
void gru_step_kernel(const float* __restrict__ xsmall,
                     const float* __restrict__ lastval,
                     const float* __restrict__ xbig,
                     const float* __restrict__ Wih,
                     const float* __restrict__ bih,
                     const float* __restrict__ Whh,
                     const float* __restrict__ bhh,
                     const float* __restrict__ h_cur,
                     float* __restrict__ h_nxt,
                     int t)
{
    const int jt = blockIdx.x, bt = blockIdx.y;
    const int tx = threadIdx.x & 31, ty = threadIdx.x >> 5;
    const int j0 = jt * BN, b0 = bt * BM;
    const int jj = j0 + tx;

    __shared__ float4 hs4[BM * (KT/4)];
    __shared__ float4 wh4[3][BN * (KT/4)];
    __shared__ float4 xs4[(MODE==1) ? (BM*(KT/4)) : 1];
    __shared__ float4 wi4[(MODE==1) ? 3 : 1][(MODE==1) ? (BN*(KT/4)) : 1];

    float Ar[4]  = {0.f,0.f,0.f,0.f};
    float Az[4]  = {0.f,0.f,0.f,0.f};
    float Ain[4] = {0.f,0.f,0.f,0.f};
    float Ahn[4] = {0.f,0.f,0.f,0.f};

    if constexpr (MODE == 0) {
        #pragma unroll
        for (int ib = 0; ib < 4; ++ib) {
            const int b = b0 + ty + 8*ib;
            const float* xp = xsmall + ((size_t)b*TT + t)*8;
            #pragma unroll
            for (int i = 0; i < 8; ++i) {
                const float xi = xp[i];
                Ar[ib]  = fmaf(xi, Wih[(size_t)jj*8 + i],        Ar[ib]);
                Az[ib]  = fmaf(xi, Wih[(size_t)(512+jj)*8 + i],  Az[ib]);
                Ain[ib] = fmaf(xi, Wih[(size_t)(1024+jj)*8 + i], Ain[ib]);
            }
        }
    }
    if constexpr (MODE == 2) {
        #pragma unroll
        for (int ib = 0; ib < 4; ++ib) {
            const int b = b0 + ty + 8*ib;
            const float* xp = xsmall + ((size_t)b*HOR + t)*8;
            const float x0 = lastval[b];
            Ar[ib]  = x0 * Wih[(size_t)jj*9];
            Az[ib]  = x0 * Wih[(size_t)(512+jj)*9];
            Ain[ib] = x0 * Wih[(size_t)(1024+jj)*9];
            #pragma unroll
            for (int i = 1; i < 9; ++i) {
                const float xi = xp[i-1];
                Ar[ib]  = fmaf(xi, Wih[(size_t)jj*9 + i],        Ar[ib]);
                Az[ib]  = fmaf(xi, Wih[(size_t)(512+jj)*9 + i],  Az[ib]);
                Ain[ib] = fmaf(xi, Wih[(size_t)(1024+jj)*9 + i], Ain[ib]);
            }
        }
    }

    const int ldb = threadIdx.x >> 3;   // 0..31 (row)
    const int ldk = threadIdx.x & 7;    // 0..7  (k-float4)

    for (int kt = 0; kt < HD/KT; ++kt) {
        const int kbase = kt*KT + ldk*4;
        hs4[ldb*8 + ldk] = *(const float4*)(h_cur + (size_t)(b0+ldb)*HD + kbase);
        #pragma unroll
        for (int g = 0; g < 3; ++g) {
            const size_t row = (size_t)g*HD + j0 + ldb;
            wh4[g][ldb*8 + (ldk ^ (ldb & 7))] = *(const float4*)(Whh + row*HD + kbase);
        }
        if constexpr (MODE == 1) {
            xs4[ldb*8 + ldk] = *(const float4*)(xbig + (size_t)(b0+ldb)*HD + kbase);
            #pragma unroll
            for (int g = 0; g < 3; ++g) {
                const size_t row = (size_t)g*HD + j0 + ldb;
                wi4[g][ldb*8 + (ldk ^ (ldb & 7))] = *(const float4*)(Wih + row*HD + kbase);
            }
        }
        __syncthreads();

        #pragma unroll
        for (int k4 = 0; k4 < KT/4; ++k4) {
            const int widx = tx*8 + (k4 ^ (tx & 7));
            const float4 wr = wh4[0][widx];
            const float4 wz = wh4[1][widx];
            const float4 wn = wh4[2][widx];
            float4 vr, vz, vn;
            if constexpr (MODE == 1) { vr = wi4[0][widx]; vz = wi4[1][widx]; vn = wi4[2][widx]; }
            #pragma unroll
            for (int ib = 0; ib < 4; ++ib) {
                const float4 hv = hs4[(ty + 8*ib)*8 + k4];
                Ar[ib]  = fmaf(hv.x, wr.x, fmaf(hv.y, wr.y, fmaf(hv.z, wr.z, fmaf(hv.w, wr.w, Ar[ib]))));
                Az[ib]  = fmaf(hv.x, wz.x, fmaf(hv.y, wz.y, fmaf(hv.z, wz.z, fmaf(hv.w, wz.w, Az[ib]))));
                Ahn[ib] = fmaf(hv.x, wn.x, fmaf(hv.y, wn.y, fmaf(hv.z, wn.z, fmaf(hv.w, wn.w, Ahn[ib]))));
                if constexpr (MODE == 1) {
                    const float4 xv = xs4[(ty + 8*ib)*8 + k4];
                    Ar[ib]  = fmaf(xv.x, vr.x, fmaf(xv.y, vr.y, fmaf(xv.z, vr.z, fmaf(xv.w, vr.w, Ar[ib]))));
                    Az[ib]  = fmaf(xv.x, vz.x, fmaf(xv.y, vz.y, fmaf(xv.z, vz.z, fmaf(xv.w, vz.w, Az[ib]))));
                    Ain[ib] = fmaf(xv.x, vn.x, fmaf(xv.y, vn.y, fmaf(xv.z, vn.z, fmaf(xv.w, vn.w, Ain[ib]))));
                }
            }
        }
        __syncthreads();
    }

    const float brc  = bih[jj]      + bhh[jj];
    const float bzc  = bih[512+jj]  + bhh[512+jj];
    const float bni  = bih[1024+jj];
    const float bnh  = bhh[1024+jj];
    #pragma unroll
    for (int ib = 0; ib < 4; ++ib) {
        const int b = b0 + ty + 8*ib;
        const float hprev = h_cur[(size_t)b*HD + jj];
        const float r = sigmoidf_(Ar[ib] + brc);
        const float z = sigmoidf_(Az[ib] + bzc);
        const float n = tanhf(Ain[ib] + bni + r * (Ahn[ib] + bnh));
        h_nxt[(size_t)b*HD + jj] = (1.f - z) * n + z * hprev;
    }
}

__global__ __launch_bounds__(256)
void dec_init_kernel(const float* __restrict__ h1, const float* __restrict__ W,
                     const float* __restrict__ bias, float* __restrict__ out)
{
    const int jt = blockIdx.x, bt = blockIdx.y;
    const int tx = threadIdx.x & 31, ty = threadIdx.x >> 5;
    const int j0 = jt * BN, b0 = bt * BM;
    const int jj = j0 + tx;
    __shared__ float4 hs4[BM*8];
    __shared__ float4 ws4[BN*8];
    float A[4] = {0.f,0.f,0.f,0.f};
    const int ldb = threadIdx.x >> 3, ldk = threadIdx.x & 7;
    for (int kt = 0; kt < HD/KT; ++kt) {
        const int kbase = kt*KT + ldk*4;
        hs4[ldb*8 + ldk] = *(const float4*)(h1 + (size_t)(b0+ldb)*HD + kbase);
        ws4[ldb*8 + (ldk ^ (ldb & 7))] = *(const float4*)(W + (size_t)(j0+ldb)*HD + kbase);
        __syncthreads();
        #pragma unroll
        for (int k4 = 0; k4 < 8; ++k4) {
            const float4 w = ws4[tx*8 + (k4 ^ (tx & 7))];
            #pragma unroll
            for (int ib = 0; ib < 4; ++ib) {
                const float4 hv = hs4[(ty + 8*ib)*8 + k4];
                A[ib] = fmaf(hv.x, w.x, fmaf(hv.y, w.y, fmaf(hv.z, w.z, fmaf(hv.w, w.w, A[ib]))));
            }
        }
        __syncthreads();
    }
    #pragma unroll
    for (int ib = 0; ib < 4; ++ib) {
        const int b = b0 + ty + 8*ib;
        out[(size_t)b*HD + jj] = A[ib] + bias[jj];
    }
}

__global__ __launch_bounds__(64)
void pred_kernel(const float* __restrict__ hid, const float* __restrict__ fcW,
                 const float* __restrict__ fcb, float* __restrict__ lastval,
                 float* __restrict__ out, int s)
{
    const int b = blockIdx.x;
    const int lane = threadIdx.x;
    float sum = 0.f;
    #pragma unroll
    for (int j = 0; j < 8; ++j)
        sum += hid[(size_t)b*HD + lane + 64*j] * fcW[lane + 64*j];
    #pragma unroll
    for (int off = 32; off > 0; off >>= 1) sum += __shfl_down(sum, off);
    if (lane == 0) {
        const float p = sum + fcb[0];
        out[(size_t)b*HOR + s] = p;
        lastval[b] = p;
    }
}

__global__ void lv_init_kernel(const float* __restrict__ src, float* __restrict__ lastval)
{
    const int b = threadIdx.x + blockIdx.x * blockDim.x;
    if (b < BB) lastval[b] = src[((size_t)b*TT + (TT-1))*8];
}

extern "C" void kernel_launch(void* const* d_in, const int* in_sizes, int n_in,
                              void* d_out, int out_size, void* d_ws, size_t ws_size,
                              hipStream_t stream)
{
    const float* src   = (const float*)d_in[0];
    const float* tff   = (const float*)d_in[1];
    const float* Wih0  = (const float*)d_in[2];
    const float* Whh0  = (const float*)d_in[3];
    const float* bih0  = (const float*)d_in[4];
    const float* bhh0  = (const float*)d_in[5];
    const float* Wih1  = (const float*)d_in[6];
    const float* Whh1  = (const float*)d_in[7];
    const float* bih1  = (const float*)d_in[8];
    const float* bhh1  = (const float*)d_in[9];
    const float* dec0W = (const float*)d_in[10];
    const float* dec0b = (const float*)d_in[11];
    const float* cWih  = (const float*)d_in[12];
    const float* cWhh  = (const float*)d_in[13];
    const float* cbih  = (const float*)d_in[14];
    const float* cbhh  = (const float*)d_in[15];
    const float* fcW   = (const float*)d_in[16];
    const float* fcb   = (const float*)d_in[17];
    float* out = (float*)d_out;

    float* ws = (float*)d_ws;
    const size_t N1 = (size_t)BB * HD;
    float* h0b[2] = { ws,          ws + 2*N1 };
    float* h1b[2] = { ws + N1,     ws + 3*N1 };
    float* dh[2]  = { ws + 4*N1,   ws + 5*N1 };
    float* lv     = ws + 6*N1;

    // h0[0] and h1[0] (adjacent) must start at zero; ws is poisoned each call.
    hipMemsetAsync(ws, 0, 2*N1*sizeof(float), stream);

    dim3 grid(HD/BN, BB/BM), blk(256);
    for (int t = 0; t < TT; ++t) {
        gru_step_kernel<0><<<grid, blk, 0, stream>>>(src, nullptr, nullptr,
            Wih0, bih0, Whh0, bhh0, h0b[t&1], h0b[(t+1)&1], t);
        gru_step_kernel<1><<<grid, blk, 0, stream>>>(nullptr, nullptr, h0b[(t+1)&1],
            Wih1, bih1, Whh1, bhh1, h1b[t&1], h1b[(t+1)&1], t);
    }
    // 336 is even -> final layer-1 state sits in h1b[0]
    dec_init_kernel<<<grid, blk, 0, stream>>>(h1b[0], dec0W, dec0b, dh[0]);
    lv_init_kernel<<<1, 512, 0, stream>>>(src, lv);
    for (int s = 0; s < HOR; ++s) {
        gru_step_kernel<2><<<grid, blk, 0, stream>>>(tff, lv, nullptr,
            cWih, cbih, cWhh, cbhh, dh[s&1], dh[(s+1)&1], s);
        pred_kernel<<<BB, 64, 0, stream>>>(dh[(s+1)&1], fcW, fcb, lv, out, s);
    }
}

// Round 2
// 7268.050 us; speedup vs baseline: 3.8113x; 3.8113x over previous
//
#include <hip/hip_runtime.h>
#include <math.h>

typedef _Float16 half_t;
typedef _Float16 half8 __attribute__((ext_vector_type(8)));
typedef float floatx16 __attribute__((ext_vector_type(16)));

#define HD 512
#define BB 512
#define TT 336
#define HOR 48

__device__ __forceinline__ float sig_(float x) { return 1.0f / (1.0f + __expf(-x)); }

// ---------------------------------------------------------------------------
// Weight prep: fp32 [rows][512] row-major -> fp16 frag-linear B layout for
// mfma_f32_32x32x16_f16.  B-frag: col = lane&31, k = (lane>>5)*8 + i.
// B'[nt][kc][lane][8] with nt=j/32, kc=k/16, lane=(j&31)+32*((k>>3)&1).
// ---------------------------------------------------------------------------
__global__ __launch_bounds__(256)
void prep_w(const float* __restrict__ W, half_t* __restrict__ D, int rows)
{
    const int idx = blockIdx.x * 256 + threadIdx.x;   // (j, k8)
    if (idx >= rows * 64) return;
    const int j = idx >> 6, k8 = idx & 63;            // k = k8*8
    const float4 lo = *(const float4*)(W + (size_t)j * 512 + k8 * 8);
    const float4 hi = *(const float4*)(W + (size_t)j * 512 + k8 * 8 + 4);
    half8 h;
    h[0] = (half_t)lo.x; h[1] = (half_t)lo.y; h[2] = (half_t)lo.z; h[3] = (half_t)lo.w;
    h[4] = (half_t)hi.x; h[5] = (half_t)hi.y; h[6] = (half_t)hi.z; h[7] = (half_t)hi.w;
    const size_t dst = ((size_t)((j >> 5) * 32 + (k8 >> 1)) * 64 + (j & 31) + 32 * (k8 & 1)) * 8;
    *(half8*)(D + dst) = h;
}

// ---------------------------------------------------------------------------
// GEMM: C[b][j] = sum_k A[b][k] * W[j][k].  A fp16 row-major [512][512],
// B fp16 frag-linear (prep_w), C fp32 row-major [512][NT*64].
// Block: 256 thr = 4 waves, tile 64x64, waves split K (128 each), LDS reduce.
// Barrier-free main loop (no LDS staging; frags loaded direct from global).
// ---------------------------------------------------------------------------
template<int NT>
__global__ __launch_bounds__(256)
void gemm_k(const half_t* __restrict__ A0, const half_t* __restrict__ B0, float* __restrict__ C0,
            const half_t* __restrict__ A1, const half_t* __restrict__ B1, float* __restrict__ C1,
            const half_t* __restrict__ A2, const half_t* __restrict__ B2, float* __restrict__ C2)
{
    const half_t* A; const half_t* B; float* C;
    if (blockIdx.z == 0)      { A = A0; B = B0; C = C0; }
    else if (blockIdx.z == 1) { A = A1; B = B1; C = C1; }
    else                      { A = A2; B = B2; C = C2; }

    const int lane = threadIdx.x & 63, wv = threadIdx.x >> 6;
    const int j0 = blockIdx.x * 64, b0 = blockIdx.y * 64;
    const int N = NT * 64;
    const int r32 = lane & 31, khalf = lane >> 5;

    floatx16 acc[2][2] = {};

    // A: row = b0 + mi*32 + (lane&31), k = wv*128 + kc*16 + khalf*8 (+i)
    const half_t* Ab = A + (size_t)(b0 + r32) * HD + wv * 128 + khalf * 8;
    // B: idx = ((nt*32 + (k>>4))*64 + lane)*8 ; k>>4 = wv*8 + kc
    const half_t* Bb = B + ((size_t)((j0 >> 5) * 32 + wv * 8) * 64 + lane) * 8;

    #pragma unroll
    for (int kc = 0; kc < 8; ++kc) {
        const half8 a0 = *(const half8*)(Ab + kc * 16);
        const half8 a1 = *(const half8*)(Ab + 32 * HD + kc * 16);
        const half8 w0 = *(const half8*)(Bb + kc * 64 * 8);
        const half8 w1 = *(const half8*)(Bb + (32 * 64 + kc * 64) * 8);
        acc[0][0] = __builtin_amdgcn_mfma_f32_32x32x16_f16(a0, w0, acc[0][0], 0, 0, 0);
        acc[0][1] = __builtin_amdgcn_mfma_f32_32x32x16_f16(a0, w1, acc[0][1], 0, 0, 0);
        acc[1][0] = __builtin_amdgcn_mfma_f32_32x32x16_f16(a1, w0, acc[1][0], 0, 0, 0);
        acc[1][1] = __builtin_amdgcn_mfma_f32_32x32x16_f16(a1, w1, acc[1][1], 0, 0, 0);
    }

    // Cross-wave K reduction, one 32x32 quadrant at a time (16 KB LDS).
    __shared__ float red[4][1024];
    const int jl = threadIdx.x & 31;
    const int rbase = threadIdx.x >> 5;   // 0..7
    #pragma unroll
    for (int mi = 0; mi < 2; ++mi)
    #pragma unroll
    for (int ni = 0; ni < 2; ++ni) {
        __syncthreads();
        #pragma unroll
        for (int rg = 0; rg < 16; ++rg)
            red[wv][rg * 64 + lane] = acc[mi][ni][rg];
        __syncthreads();
        #pragma unroll
        for (int q = 0; q < 4; ++q) {
            const int r = rbase + 8 * q;                        // 0..31 (b_local)
            const int e = ((r & 3) + 4 * (r >> 3)) * 64 + jl + 32 * ((r >> 2) & 1);
            const float s = red[0][e] + red[1][e] + red[2][e] + red[3][e];
            C[(size_t)(b0 + mi * 32 + r) * N + j0 + ni * 32 + jl] = s;
        }
    }
}

// ---------------------------------------------------------------------------
// Gate kernels (memory-bound elementwise).
// ---------------------------------------------------------------------------
__global__ __launch_bounds__(256)
void gates_enc(int s, int doL0, int doL1,
               const float* __restrict__ src, const float* __restrict__ Wih0,
               const float* __restrict__ bih0, const float* __restrict__ bhh0,
               const float* __restrict__ gh0,
               const float* __restrict__ h0p, float* __restrict__ h0o, half_t* __restrict__ h0o16,
               const float* __restrict__ gi1, const float* __restrict__ gh1,
               const float* __restrict__ bih1, const float* __restrict__ bhh1,
               const float* __restrict__ h1p, float* __restrict__ h1o, half_t* __restrict__ h1o16)
{
    const int g = blockIdx.x * 256 + threadIdx.x;   // 512*512
    const int b = g >> 9, j = g & 511;
    const size_t base = (size_t)b * 1536 + j;
    if (doL0) {
        const float* xp = src + ((size_t)b * TT + s) * 8;
        float gr = 0.f, gz = 0.f, gn = 0.f;
        #pragma unroll
        for (int i = 0; i < 8; ++i) {
            const float xi = xp[i];
            gr = fmaf(xi, Wih0[(size_t)j * 8 + i], gr);
            gz = fmaf(xi, Wih0[(size_t)(512 + j) * 8 + i], gz);
            gn = fmaf(xi, Wih0[(size_t)(1024 + j) * 8 + i], gn);
        }
        const float r = sig_(gr + bih0[j] + gh0[base] + bhh0[j]);
        const float z = sig_(gz + bih0[512 + j] + gh0[base + 512] + bhh0[512 + j]);
        const float n = tanhf(gn + bih0[1024 + j] + r * (gh0[base + 1024] + bhh0[1024 + j]));
        const float h = (1.f - z) * n + z * h0p[g];
        h0o[g] = h; h0o16[g] = (half_t)h;
    }
    if (doL1) {
        const float r = sig_(gi1[base] + gh1[base] + bih1[j] + bhh1[j]);
        const float z = sig_(gi1[base + 512] + gh1[base + 512] + bih1[512 + j] + bhh1[512 + j]);
        const float n = tanhf(gi1[base + 1024] + bih1[1024 + j] + r * (gh1[base + 1024] + bhh1[1024 + j]));
        const float h = (1.f - z) * n + z * h1p[g];
        h1o[g] = h; h1o16[g] = (half_t)h;
    }
}

__global__ __launch_bounds__(256)
void gates_dec(int s, const float* __restrict__ tff, const float* __restrict__ lv,
               const float* __restrict__ cWih, const float* __restrict__ cbih,
               const float* __restrict__ cbhh, const float* __restrict__ gh,
               const float* __restrict__ hp, float* __restrict__ ho, half_t* __restrict__ ho16)
{
    const int g = blockIdx.x * 256 + threadIdx.x;
    const int b = g >> 9, j = g & 511;
    const size_t base = (size_t)b * 1536 + j;
    const float* xp = tff + ((size_t)b * HOR + s) * 8;
    const float x0 = lv[b];
    float gr = x0 * cWih[(size_t)j * 9];
    float gz = x0 * cWih[(size_t)(512 + j) * 9];
    float gn = x0 * cWih[(size_t)(1024 + j) * 9];
    #pragma unroll
    for (int i = 0; i < 8; ++i) {
        const float xi = xp[i];
        gr = fmaf(xi, cWih[(size_t)j * 9 + 1 + i], gr);
        gz = fmaf(xi, cWih[(size_t)(512 + j) * 9 + 1 + i], gz);
        gn = fmaf(xi, cWih[(size_t)(1024 + j) * 9 + 1 + i], gn);
    }
    const float r = sig_(gr + cbih[j] + gh[base] + cbhh[j]);
    const float z = sig_(gz + cbih[512 + j] + gh[base + 512] + cbhh[512 + j]);
    const float n = tanhf(gn + cbih[1024 + j] + r * (gh[base + 1024] + cbhh[1024 + j]));
    const float h = (1.f - z) * n + z * hp[g];
    ho[g] = h; ho16[g] = (half_t)h;
}

__global__ __launch_bounds__(256)
void bias_h(const float* __restrict__ Cin, const float* __restrict__ bias,
            float* __restrict__ o, half_t* __restrict__ o16)
{
    const int g = blockIdx.x * 256 + threadIdx.x;
    const float v = Cin[g] + bias[g & 511];
    o[g] = v; o16[g] = (half_t)v;
}

__global__ __launch_bounds__(64)
void pred_kernel(const float* __restrict__ hid, const float* __restrict__ fcW,
                 const float* __restrict__ fcb, float* __restrict__ lastval,
                 float* __restrict__ out, int s)
{
    const int b = blockIdx.x;
    const int lane = threadIdx.x;
    float sum = 0.f;
    #pragma unroll
    for (int j = 0; j < 8; ++j)
        sum += hid[(size_t)b * HD + lane + 64 * j] * fcW[lane + 64 * j];
    #pragma unroll
    for (int off = 32; off > 0; off >>= 1) sum += __shfl_down(sum, off);
    if (lane == 0) {
        const float p = sum + fcb[0];
        out[(size_t)b * HOR + s] = p;
        lastval[b] = p;
    }
}

__global__ void lv_init_kernel(const float* __restrict__ src, float* __restrict__ lastval)
{
    const int b = threadIdx.x + blockIdx.x * blockDim.x;
    if (b < BB) lastval[b] = src[((size_t)b * TT + (TT - 1)) * 8];
}

// ---------------------------------------------------------------------------
extern "C" void kernel_launch(void* const* d_in, const int* in_sizes, int n_in,
                              void* d_out, int out_size, void* d_ws, size_t ws_size,
                              hipStream_t stream)
{
    const float* src   = (const float*)d_in[0];
    const float* tff   = (const float*)d_in[1];
    const float* Wih0  = (const float*)d_in[2];
    const float* Whh0  = (const float*)d_in[3];
    const float* bih0  = (const float*)d_in[4];
    const float* bhh0  = (const float*)d_in[5];
    const float* Wih1  = (const float*)d_in[6];
    const float* Whh1  = (const float*)d_in[7];
    const float* bih1  = (const float*)d_in[8];
    const float* bhh1  = (const float*)d_in[9];
    const float* dec0W = (const float*)d_in[10];
    const float* dec0b = (const float*)d_in[11];
    const float* cWih  = (const float*)d_in[12];
    const float* cWhh  = (const float*)d_in[13];
    const float* cbih  = (const float*)d_in[14];
    const float* cbhh  = (const float*)d_in[15];
    const float* fcW   = (const float*)d_in[16];
    const float* fcb   = (const float*)d_in[17];
    float* out = (float*)d_out;
    float* ws  = (float*)d_ws;

    constexpr size_t N1 = (size_t)BB * HD;    // 262144
    constexpr size_t NHalf = N1 / 2;          // fp16 buffer in float slots
    constexpr size_t NG = (size_t)BB * 1536;  // 786432

    // zero region (one memset): h0f32[0], h1f32[1], h0f16[0], h1f16[1], gh0
    float*  h0f32[2]; float* h1f32[2]; half_t* h0f16[2]; half_t* h1f16[2];
    h0f32[0] = ws;
    h1f32[1] = ws + N1;
    h0f16[0] = (half_t*)(ws + 2 * N1);
    h1f16[1] = (half_t*)(ws + 2 * N1 + NHalf);
    float* gh0buf = ws + 2 * N1 + 2 * NHalf;
    const size_t zero_floats = 2 * N1 + 2 * NHalf + NG;   // 1,572,864

    size_t off = zero_floats;
    h0f32[1] = ws + off; off += N1;
    h1f32[0] = ws + off; off += N1;
    h0f16[1] = (half_t*)(ws + off); off += NHalf;
    h1f16[0] = (half_t*)(ws + off); off += NHalf;
    float* gi1buf = ws + off; off += NG;
    float* gh1buf = ws + off; off += NG;
    float* hdf32[2]; half_t* hdf16[2];
    hdf32[0] = ws + off; off += N1;
    hdf32[1] = ws + off; off += N1;
    hdf16[0] = (half_t*)(ws + off); off += NHalf;
    hdf16[1] = (half_t*)(ws + off); off += NHalf;
    float* lv = ws + off; off += 1024;
    half_t* Bwhh0 = (half_t*)(ws + off); off += 393216;
    half_t* Bwih1 = (half_t*)(ws + off); off += 393216;
    half_t* Bwhh1 = (half_t*)(ws + off); off += 393216;
    half_t* Bcwhh = (half_t*)(ws + off); off += 393216;
    half_t* Bdec0 = (half_t*)(ws + off); off += 131072;

    // --- one-time prep ---
    hipMemsetAsync(ws, 0, zero_floats * sizeof(float), stream);
    prep_w<<<384, 256, 0, stream>>>(Whh0, Bwhh0, 1536);
    prep_w<<<384, 256, 0, stream>>>(Wih1, Bwih1, 1536);
    prep_w<<<384, 256, 0, stream>>>(Whh1, Bwhh1, 1536);
    prep_w<<<384, 256, 0, stream>>>(cWhh, Bcwhh, 1536);
    prep_w<<<128, 256, 0, stream>>>(dec0W, Bdec0, 512);
    lv_init_kernel<<<1, 512, 0, stream>>>(src, lv);

    // --- encoder supersteps: L0 at t=s (s<=335), L1 at t=s-1 (s>=1) ---
    for (int s = 0; s <= TT; ++s) {
        const int doL0 = (s <= TT - 1), doL1 = (s >= 1);
        if (doL1) {
            if (doL0) {
                gemm_k<24><<<dim3(24, 8, 3), 256, 0, stream>>>(
                    h0f16[s & 1], Bwhh0, gh0buf,      // gh0 = h0(s-1) @ Whh0^T
                    h0f16[s & 1], Bwih1, gi1buf,      // gi1 = h0(s-1) @ Wih1^T
                    h1f16[s & 1], Bwhh1, gh1buf);     // gh1 = h1(s-2) @ Whh1^T
            } else {
                gemm_k<24><<<dim3(24, 8, 2), 256, 0, stream>>>(
                    h0f16[s & 1], Bwih1, gi1buf,
                    h1f16[s & 1], Bwhh1, gh1buf,
                    h1f16[s & 1], Bwhh1, gh1buf);
            }
        }
        gates_enc<<<1024, 256, 0, stream>>>(s, doL0, doL1,
            src, Wih0, bih0, bhh0, gh0buf,
            h0f32[s & 1], h0f32[(s + 1) & 1], h0f16[(s + 1) & 1],
            gi1buf, gh1buf, bih1, bhh1,
            h1f32[s & 1], h1f32[(s + 1) & 1], h1f16[(s + 1) & 1]);
    }
    // final h1 = h1(335) in index (TT+1)&1 = 1

    // --- decoder init: hidden = h1_final @ dec0W^T + dec0b ---
    gemm_k<8><<<dim3(8, 8, 1), 256, 0, stream>>>(
        h1f16[1], Bdec0, gh0buf, h1f16[1], Bdec0, gh0buf, h1f16[1], Bdec0, gh0buf);
    bias_h<<<1024, 256, 0, stream>>>(gh0buf, dec0b, hdf32[0], hdf16[0]);

    // --- decoder loop ---
    for (int s = 0; s < HOR; ++s) {
        gemm_k<24><<<dim3(24, 8, 1), 256, 0, stream>>>(
            hdf16[s & 1], Bcwhh, gh0buf,
            hdf16[s & 1], Bcwhh, gh0buf,
            hdf16[s & 1], Bcwhh, gh0buf);
        gates_dec<<<1024, 256, 0, stream>>>(s, tff, lv, cWih, cbih, cbhh, gh0buf,
            hdf32[s & 1], hdf32[(s + 1) & 1], hdf16[(s + 1) & 1]);
        pred_kernel<<<BB, 64, 0, stream>>>(hdf32[(s + 1) & 1], fcW, fcb, lv, out, s);
    }
}